// Round 14
// baseline (578.940 us; speedup 1.0000x reference)
//
#include <hip/hip_runtime.h>

// ---------------------------------------------------------------------------
// SRU LM: emb-gather -> SRU(512->1024,k4) -> 4x SRU(1024,k3) -> SRU(1024->512,k4)
//         -> logits = h @ emb^T + bias
// L=128 B=32 E=512 D=1024 V=32000 MID=4
// Round 14 = round 13 (544us) + NON-TEMPORAL stores for the bf16 U epilogue
// as well: U is write-once/read-once-by-scan/dead, so keep L2 for the A/B
// panels the GEMM itself is re-reading (round-13: same fix on logits C was
// -68us).  h outputs (re-read 24-32x as next A) remain normally cached.
// GEMM: 128x128 tile (m97 structure), 16x16x32 MFMA, 256 thr, single-buffered
// 32KiB LDS, ~4 blocks/CU; XCD-bijective swizzle, m-fastest tile order;
// write-combined epilogue; L1 A-operand = fused token gather.
// Scans: 4-deep pipelined, bf16 U.  U bf16 scratch in d_out.
// ---------------------------------------------------------------------------

typedef __attribute__((ext_vector_type(8))) __bf16 bf16x8;
typedef __attribute__((ext_vector_type(4))) float f32x4;
typedef __attribute__((ext_vector_type(4))) float float4v;
typedef __attribute__((ext_vector_type(4))) unsigned short u16x4;

__device__ __forceinline__ unsigned short f2bf(float f) {
  unsigned int u = __builtin_bit_cast(unsigned int, f);
  u += 0x7fffu + ((u >> 16) & 1u);          // RNE
  return (unsigned short)(u >> 16);
}
__device__ __forceinline__ float bf2f(unsigned short v) {
  unsigned int u = ((unsigned int)v) << 16;
  return __builtin_bit_cast(float, u);
}

#define GLDS16(SRC, DST)                                                      \
  __builtin_amdgcn_global_load_lds(                                           \
      (__attribute__((address_space(1))) void*)(SRC),                         \
      (__attribute__((address_space(3))) void*)(DST), 16, 0, 0)

// ---------------------------------------------------------------------------
// 128x128-tile GEMM (m97 structure).  C[m][n] = sum_k A[m][k]*B[n][k].
// A:(M,K) bf16, B:(N,K) bf16.  BF16OUT: C bf16, NT stores (U scratch path:
// write-once/read-once) else C fp32 (+bias, NT stores — logits path).
// GATHER: A-row r sourced from A + x[m0+r]*K (token gather; A=embbf, K=512).
// M%128==0, N%128==0, K%64==0, grid%8==0.  256 thr = 4 waves (2x2),
// 64x64 out/wave (4x4 frags).  Single-buffered BK=64.
// LDS slot-swizzle: LDS[row][slot] = global 16B-slot (slot ^ (row&7)).
// Tile order m-fastest: consecutive wg on an XCD share B n-panel (L2).
// ---------------------------------------------------------------------------
template <bool BF16OUT, bool GATHER>
__global__ __launch_bounds__(256, 4)
void gemm128(const unsigned short* __restrict__ A,
             const unsigned short* __restrict__ B,
             void* __restrict__ Cv, const float* __restrict__ bias,
             const int* __restrict__ xrow,
             int M, int N, int K, int tiles_m) {
  __shared__ __align__(16) unsigned short As[128 * 64];
  __shared__ __align__(16) unsigned short Bs[128 * 64];
  __shared__ int xs[128];

  const int tid  = threadIdx.x;
  const int lane = tid & 63;
  const int wave = tid >> 6;
  const int wm = wave >> 1, wn = wave & 1;

  // bijective XCD swizzle (nwg % 8 == 0 for all our grids)
  const int nwg  = gridDim.x;
  const int orig = blockIdx.x;
  const int wg   = (orig & 7) * (nwg >> 3) + (orig >> 3);
  const int by = wg % tiles_m, bx = wg / tiles_m;   // m-fastest
  const int m0 = by * 128, n0 = bx * 128;

  if constexpr (GATHER) {
    if (tid < 128) xs[tid] = xrow[m0 + tid];
    __syncthreads();
  }

  const int srow  = lane >> 3;
  const int sslot = (lane & 7) ^ srow;
  const int fr = lane & 15;
  const int s0 = (lane >> 4) ^ (lane & 7);
  const int lg = lane >> 4;

  f32x4 acc[4][4] = {};

  const int ksteps = K >> 6;
  for (int ks = 0; ks < ksteps; ++ks) {
    const int k0 = ks << 6;
#pragma unroll
    for (int j = 0; j < 4; ++j) {
      const int rbase = (j * 4 + wave) * 8;          // wave-uniform
      const int r = rbase + srow;
      const unsigned short* sa;
      if constexpr (GATHER)
        sa = A + (size_t)xs[r] * K + k0 + sslot * 8;
      else
        sa = A + (size_t)(m0 + r) * K + k0 + sslot * 8;
      const unsigned short* sb = B + (size_t)(n0 + r) * K + k0 + sslot * 8;
      GLDS16(sa, &As[rbase * 64]);
      GLDS16(sb, &Bs[rbase * 64]);
    }
    __syncthreads();
#pragma unroll
    for (int kk = 0; kk < 2; ++kk) {
      const int slot = s0 ^ (kk << 2);
      bf16x8 a[4], b[4];
#pragma unroll
      for (int m = 0; m < 4; ++m)
        a[m] = *(const bf16x8*)&As[(wm * 64 + m * 16 + fr) * 64 + slot * 8];
#pragma unroll
      for (int n = 0; n < 4; ++n)
        b[n] = *(const bf16x8*)&Bs[(wn * 64 + n * 16 + fr) * 64 + slot * 8];
#pragma unroll
      for (int m = 0; m < 4; ++m)
#pragma unroll
        for (int n = 0; n < 4; ++n)
          acc[m][n] = __builtin_amdgcn_mfma_f32_16x16x32_bf16(a[m], b[n],
                                                              acc[m][n], 0, 0, 0);
    }
    __syncthreads();
  }

  // epilogue, write-combined order (m,r outer / n inner — round-8 lesson),
  // non-temporal both paths (write-once data; keep L2/L3 for A/B panels).
  if constexpr (BF16OUT) {
    unsigned short* C = (unsigned short*)Cv;
#pragma unroll
    for (int m = 0; m < 4; ++m) {
      const int row = m0 + wm * 64 + m * 16 + lg * 4;
#pragma unroll
      for (int r = 0; r < 4; ++r) {
        unsigned short* Crow = C + (size_t)(row + r) * N + n0 + wn * 64 + fr;
#pragma unroll
        for (int n = 0; n < 4; ++n)
          __builtin_nontemporal_store(f2bf(acc[m][n][r]), &Crow[n * 16]);
      }
    }
  } else {
    float* C = (float*)Cv;
    float bv[4];
#pragma unroll
    for (int n = 0; n < 4; ++n)
      bv[n] = bias ? bias[n0 + wn * 64 + n * 16 + fr] : 0.0f;
#pragma unroll
    for (int m = 0; m < 4; ++m) {
      const int row = m0 + wm * 64 + m * 16 + lg * 4;
#pragma unroll
      for (int r = 0; r < 4; ++r) {
        float* Crow = C + (size_t)(row + r) * N + n0 + wn * 64 + fr;
#pragma unroll
        for (int n = 0; n < 4; ++n)
          __builtin_nontemporal_store(acc[m][n][r] + bv[n], &Crow[n * 16]);
      }
    }
  }
}

// ---------------------------------------------------------------------------
// SRU scan, 4-deep software-pipelined.  One thread per (b,d) chain, L=128.
// U is bf16 (L,B,k*n_out).  hw = U[...,3n:] if K4 else bf16 hin.
// ---------------------------------------------------------------------------
template <bool K4>
__global__ void scan_k(const unsigned short* __restrict__ U,
                       const float* __restrict__ bias,
                       const float* __restrict__ c0,
                       const unsigned short* __restrict__ hin,
                       unsigned short* __restrict__ hout, int n_out) {
  const int idx = blockIdx.x * 64 + threadIdx.x;     // 0 .. 32*n_out
  const int b = idx / n_out;
  const int d = idx - b * n_out;
  const float biasf = bias[d];
  const float biasr = bias[n_out + d];
  float c = c0[idx];
  const int rowlen = (K4 ? 4 : 3) * n_out;
  const unsigned short* Up = U + (size_t)b * rowlen + d;
  const size_t lstride = (size_t)32 * rowlen;
  const unsigned short* hp = hin + (size_t)b * n_out + d;
  unsigned short* op = hout + (size_t)b * n_out + d;
  const size_t hstride = (size_t)32 * n_out;

  float xt0, fr0, rr0, hw0, xt1, fr1, rr1, hw1;
  float xt2, fr2, rr2, hw2, xt3, fr3, rr3, hw3;

#define SRU_LOAD(S)                                                           \
  do {                                                                        \
    xt##S = bf2f(Up[0]);                                                      \
    fr##S = bf2f(Up[n_out]);                                                  \
    rr##S = bf2f(Up[2 * n_out]);                                              \
    hw##S = K4 ? bf2f(Up[3 * n_out]) : bf2f(*hp);                             \
    Up += lstride;                                                            \
    hp += hstride;                                                            \
  } while (0)

#define SRU_STEP(S)                                                           \
  do {                                                                        \
    const float f = 1.0f / (1.0f + __expf(-(fr##S + biasf)));                 \
    const float r = 1.0f / (1.0f + __expf(-(rr##S + biasr)));                 \
    c = f * c + (1.0f - f) * xt##S;                                           \
    const float e2 = __expf(2.0f * c);                                        \
    const float g = 1.0f - 2.0f / (e2 + 1.0f);                                \
    *op = f2bf(r * g + (1.0f - r) * hw##S);                                   \
    op += hstride;                                                            \
  } while (0)

  SRU_LOAD(0); SRU_LOAD(1); SRU_LOAD(2); SRU_LOAD(3);   // l = 0..3
  for (int l = 0; l < 124; l += 4) {                    // l = 0,4,...,120
    SRU_STEP(0); SRU_LOAD(0);                           // load l+4
    SRU_STEP(1); SRU_LOAD(1);
    SRU_STEP(2); SRU_LOAD(2);
    SRU_STEP(3); SRU_LOAD(3);
  }
  SRU_STEP(0); SRU_STEP(1); SRU_STEP(2); SRU_STEP(3);   // l = 124..127
#undef SRU_LOAD
#undef SRU_STEP
}

// ---------------------------------------------------------------------------
// Fused prep: emb->bf16 cvt + all 6 weight transposes (64x64 tiles ->
// 128B-per-instruction output rows).  256 thr/block.
// ---------------------------------------------------------------------------
__device__ __forceinline__ void transpose_tile64(const float* __restrict__ W,
                                                 unsigned short* __restrict__ Wt,
                                                 int K, int N, int bx, int by,
                                                 int tid) {
  __shared__ float tile[64][65];
  const int n0 = bx * 64, k0 = by * 64;
  const int tx = tid & 63, ty = tid >> 6;   // (64,4)
#pragma unroll
  for (int i = 0; i < 64; i += 4)
    tile[ty + i][tx] = W[(size_t)(k0 + ty + i) * N + n0 + tx];
  __syncthreads();
#pragma unroll
  for (int i = 0; i < 64; i += 4)
    Wt[(size_t)(n0 + ty + i) * K + k0 + tx] = f2bf(tile[tx][ty + i]);
}

__global__ void prep_k(const float* __restrict__ emb,
                       const float* __restrict__ W1,
                       const float* __restrict__ W2,
                       const float* __restrict__ W3,
                       unsigned short* __restrict__ embbf,
                       unsigned short* __restrict__ W1t,
                       unsigned short* __restrict__ W2t,
                       unsigned short* __restrict__ W3t) {
  const int blk = blockIdx.x;
  const int tid = threadIdx.x;
  if (blk < 16000) {                                   // cvt emb -> bf16
    const int i = blk * 256 + tid;
    const float4v v = ((const float4v*)emb)[i];
    u16x4 o;
    o.x = f2bf(v.x); o.y = f2bf(v.y); o.z = f2bf(v.z); o.w = f2bf(v.w);
    ((u16x4*)embbf)[i] = o;
  } else if (blk < 16512) {                            // W1: K=512 N=4096
    const int r = blk - 16000;                         // 64 x 8
    transpose_tile64(W1, W1t, 512, 4096, r & 63, r >> 6, tid);
  } else if (blk < 19584) {                            // W2[i]: K=1024 N=3072
    const int r = blk - 16512;
    const int i = r / 768, rr = r - i * 768;           // 48 x 16 per layer
    transpose_tile64(W2 + (size_t)i * 3145728, W2t + (size_t)i * 3145728,
                     1024, 3072, rr % 48, rr / 48, tid);
  } else {                                             // W3: K=1024 N=2048
    const int r = blk - 19584;                         // 32 x 16
    transpose_tile64(W3, W3t, 1024, 2048, r & 31, r >> 5, tid);
  }
}

extern "C" void kernel_launch(void* const* d_in, const int* in_sizes, int n_in,
                              void* d_out, int out_size, void* d_ws, size_t ws_size,
                              hipStream_t stream) {
  (void)in_sizes; (void)n_in; (void)out_size; (void)ws_size;
  const int*   x     = (const int*)d_in[0];
  const float* c1    = (const float*)d_in[1];
  const float* c2    = (const float*)d_in[2];
  const float* c3    = (const float*)d_in[3];
  const float* emb   = (const float*)d_in[4];
  const float* obias = (const float*)d_in[5];
  const float* W1    = (const float*)d_in[6];
  const float* b1    = (const float*)d_in[7];
  const float* W2    = (const float*)d_in[8];
  const float* b2    = (const float*)d_in[9];
  const float* W3    = (const float*)d_in[10];
  const float* b3    = (const float*)d_in[11];

  char* ws = (char*)d_ws;
  unsigned short* hbfA  = (unsigned short*)ws;                  //  8,388,608 B
  unsigned short* hbfB  = (unsigned short*)(ws + 8388608);      //  8,388,608 B
  unsigned short* embbf = (unsigned short*)(ws + 16777216);     // 32,768,000 B
  unsigned short* W1t   = (unsigned short*)(ws + 49545216);     //  4,194,304 B
  unsigned short* W2t   = (unsigned short*)(ws + 53739520);     // 25,165,824 B
  unsigned short* W3t   = (unsigned short*)(ws + 78905344);     //  4,194,304 B
  unsigned short* U = (unsigned short*)d_out;  // bf16 U scratch (<=34MB) in
                                               // d_out; logits overwrite it.

  // input prep in one launch (emb cvt + 6 transposes — independent)
  prep_k<<<20096, 256, 0, stream>>>(emb, W1, W2, W3, embbf, W1t, W2t, W3t);

  // ---- layer 1: (512 -> 1024, k=4): 32x32 = 1024 tiles, A = gather(embbf,x)
  gemm128<true, true><<<1024, 256, 0, stream>>>(embbf, W1t, U, nullptr, x,
                                                4096, 4096, 512, 32);
  scan_k<true><<<512, 64, 0, stream>>>(U, b1, c1, hbfB, hbfB, 1024);

  // ---- mid layers: 4x (1024 -> 1024, k=3): 32x24 = 768 tiles ----
  const unsigned short* hin = hbfB;
  unsigned short* hout = hbfA;
  for (int i = 0; i < 4; ++i) {
    gemm128<true, false><<<768, 256, 0, stream>>>(hin, W2t + (size_t)i * 3145728,
                                                  U, nullptr, nullptr,
                                                  4096, 3072, 1024, 32);
    scan_k<false><<<512, 64, 0, stream>>>(U, b2 + i * 2048, c2 + (size_t)i * 32768,
                                          hin, hout, 1024);
    const unsigned short* t = hin; hin = hout; hout = (unsigned short*)t;
  }

  // ---- final SRU: (1024 -> 512, k=4): 32x16 = 512 tiles ----
  gemm128<true, false><<<512, 256, 0, stream>>>(hin, W3t, U, nullptr, nullptr,
                                                4096, 2048, 1024, 32);
  scan_k<true><<<256, 64, 0, stream>>>(U, b3, c3, hout, hout, 512);

  // ---- logits: (4096 x 32000): 32x250 = 8000 tiles, fp32 + bias, NT-C ----
  gemm128<false, false><<<8000, 256, 0, stream>>>(hout, embbf, (float*)d_out,
                                                  obias, nullptr,
                                                  4096, 32000, 512, 32);
}

// Round 15
// 549.713 us; speedup vs baseline: 1.0532x; 1.0532x over previous
//
#include <hip/hip_runtime.h>

// ---------------------------------------------------------------------------
// SRU LM: emb-gather -> SRU(512->1024,k4) -> 4x SRU(1024,k3) -> SRU(1024->512,k4)
//         -> logits = h @ emb^T + bias
// L=128 B=32 E=512 D=1024 V=32000 MID=4
// Round 15 = round 13 (544us; U-NT of round 14 REVERTED: U is re-read by the
// next kernel, so NT de-cached it -> +35us.  NT only where no device kernel
// re-reads: logits C) + token gather moved from LDS (xs[128]) to 4 hoisted
// per-lane registers -> LDS exactly 32768B in ALL gemm instantiations ->
// HW may co-schedule 5 blocks/CU (launch_bounds(256,4) is a floor; no spill
// risk if VGPR>102, occupancy just stays 4).
// GEMM: 128x128 tile (m97 structure), 16x16x32 MFMA, 256 thr, single-buffered
// 32KiB LDS; XCD-bijective swizzle, m-fastest tile order; write-combined
// epilogue.  Scans: 4-deep pipelined, bf16 U.  U bf16 scratch in d_out.
// ---------------------------------------------------------------------------

typedef __attribute__((ext_vector_type(8))) __bf16 bf16x8;
typedef __attribute__((ext_vector_type(4))) float f32x4;
typedef __attribute__((ext_vector_type(4))) float float4v;
typedef __attribute__((ext_vector_type(4))) unsigned short u16x4;

__device__ __forceinline__ unsigned short f2bf(float f) {
  unsigned int u = __builtin_bit_cast(unsigned int, f);
  u += 0x7fffu + ((u >> 16) & 1u);          // RNE
  return (unsigned short)(u >> 16);
}
__device__ __forceinline__ float bf2f(unsigned short v) {
  unsigned int u = ((unsigned int)v) << 16;
  return __builtin_bit_cast(float, u);
}

#define GLDS16(SRC, DST)                                                      \
  __builtin_amdgcn_global_load_lds(                                           \
      (__attribute__((address_space(1))) void*)(SRC),                         \
      (__attribute__((address_space(3))) void*)(DST), 16, 0, 0)

// ---------------------------------------------------------------------------
// 128x128-tile GEMM (m97 structure).  C[m][n] = sum_k A[m][k]*B[n][k].
// A:(M,K) bf16, B:(N,K) bf16.  BF16OUT: C bf16 (normal stores — U is re-read
// by the scan) else C fp32 (+bias, NT stores — logits, host-only consumer).
// GATHER: A-row r sourced from A + x[m0+r]*K via hoisted per-lane token regs.
// M%128==0, N%128==0, K%64==0, grid%8==0.  256 thr = 4 waves (2x2),
// 64x64 out/wave (4x4 frags).  Single-buffered BK=64.  LDS = exactly 32 KiB.
// LDS slot-swizzle: LDS[row][slot] = global 16B-slot (slot ^ (row&7)).
// Tile order m-fastest: all CUs of an XCD share one B n-panel (L2-resident).
// ---------------------------------------------------------------------------
template <bool BF16OUT, bool GATHER>
__global__ __launch_bounds__(256, 4)
void gemm128(const unsigned short* __restrict__ A,
             const unsigned short* __restrict__ B,
             void* __restrict__ Cv, const float* __restrict__ bias,
             const int* __restrict__ xrow,
             int M, int N, int K, int tiles_m) {
  __shared__ __align__(16) unsigned short As[128 * 64];
  __shared__ __align__(16) unsigned short Bs[128 * 64];

  const int tid  = threadIdx.x;
  const int lane = tid & 63;
  const int wave = tid >> 6;
  const int wm = wave >> 1, wn = wave & 1;

  // bijective XCD swizzle (nwg % 8 == 0 for all our grids)
  const int nwg  = gridDim.x;
  const int orig = blockIdx.x;
  const int wg   = (orig & 7) * (nwg >> 3) + (orig >> 3);
  const int by = wg % tiles_m, bx = wg / tiles_m;   // m-fastest
  const int m0 = by * 128, n0 = bx * 128;

  const int srow  = lane >> 3;
  const int sslot = (lane & 7) ^ srow;
  const int fr = lane & 15;
  const int s0 = (lane >> 4) ^ (lane & 7);
  const int lg = lane >> 4;

  // gather: per-lane token for each of the 4 staged row-groups (k-invariant)
  int tokr[4];
  if constexpr (GATHER) {
#pragma unroll
    for (int j = 0; j < 4; ++j)
      tokr[j] = xrow[m0 + (j * 4 + wave) * 8 + srow];
  }

  f32x4 acc[4][4] = {};

  const int ksteps = K >> 6;
  for (int ks = 0; ks < ksteps; ++ks) {
    const int k0 = ks << 6;
#pragma unroll
    for (int j = 0; j < 4; ++j) {
      const int rbase = (j * 4 + wave) * 8;          // wave-uniform
      const unsigned short* sa;
      if constexpr (GATHER)
        sa = A + (size_t)tokr[j] * K + k0 + sslot * 8;
      else
        sa = A + (size_t)(m0 + rbase + srow) * K + k0 + sslot * 8;
      const unsigned short* sb = B + (size_t)(n0 + rbase + srow) * K + k0 + sslot * 8;
      GLDS16(sa, &As[rbase * 64]);
      GLDS16(sb, &Bs[rbase * 64]);
    }
    __syncthreads();
#pragma unroll
    for (int kk = 0; kk < 2; ++kk) {
      const int slot = s0 ^ (kk << 2);
      bf16x8 a[4], b[4];
#pragma unroll
      for (int m = 0; m < 4; ++m)
        a[m] = *(const bf16x8*)&As[(wm * 64 + m * 16 + fr) * 64 + slot * 8];
#pragma unroll
      for (int n = 0; n < 4; ++n)
        b[n] = *(const bf16x8*)&Bs[(wn * 64 + n * 16 + fr) * 64 + slot * 8];
#pragma unroll
      for (int m = 0; m < 4; ++m)
#pragma unroll
        for (int n = 0; n < 4; ++n)
          acc[m][n] = __builtin_amdgcn_mfma_f32_16x16x32_bf16(a[m], b[n],
                                                              acc[m][n], 0, 0, 0);
    }
    __syncthreads();
  }

  // epilogue, write-combined order (m,r outer / n inner — round-8 lesson)
  if constexpr (BF16OUT) {
    unsigned short* C = (unsigned short*)Cv;
#pragma unroll
    for (int m = 0; m < 4; ++m) {
      const int row = m0 + wm * 64 + m * 16 + lg * 4;
#pragma unroll
      for (int r = 0; r < 4; ++r) {
        unsigned short* Crow = C + (size_t)(row + r) * N + n0 + wn * 64 + fr;
#pragma unroll
        for (int n = 0; n < 4; ++n)
          Crow[n * 16] = f2bf(acc[m][n][r]);
      }
    }
  } else {
    // fp32 path = logits only.  Non-temporal: C write-once, host-only reader;
    // keep L2/L3 for the B panels instead of 524MB of C lines (round 13: -68us).
    float* C = (float*)Cv;
    float bv[4];
#pragma unroll
    for (int n = 0; n < 4; ++n)
      bv[n] = bias ? bias[n0 + wn * 64 + n * 16 + fr] : 0.0f;
#pragma unroll
    for (int m = 0; m < 4; ++m) {
      const int row = m0 + wm * 64 + m * 16 + lg * 4;
#pragma unroll
      for (int r = 0; r < 4; ++r) {
        float* Crow = C + (size_t)(row + r) * N + n0 + wn * 64 + fr;
#pragma unroll
        for (int n = 0; n < 4; ++n)
          __builtin_nontemporal_store(acc[m][n][r] + bv[n], &Crow[n * 16]);
      }
    }
  }
}

// ---------------------------------------------------------------------------
// SRU scan, 4-deep software-pipelined.  One thread per (b,d) chain, L=128.
// U is bf16 (L,B,k*n_out).  hw = U[...,3n:] if K4 else bf16 hin.
// ---------------------------------------------------------------------------
template <bool K4>
__global__ void scan_k(const unsigned short* __restrict__ U,
                       const float* __restrict__ bias,
                       const float* __restrict__ c0,
                       const unsigned short* __restrict__ hin,
                       unsigned short* __restrict__ hout, int n_out) {
  const int idx = blockIdx.x * 64 + threadIdx.x;     // 0 .. 32*n_out
  const int b = idx / n_out;
  const int d = idx - b * n_out;
  const float biasf = bias[d];
  const float biasr = bias[n_out + d];
  float c = c0[idx];
  const int rowlen = (K4 ? 4 : 3) * n_out;
  const unsigned short* Up = U + (size_t)b * rowlen + d;
  const size_t lstride = (size_t)32 * rowlen;
  const unsigned short* hp = hin + (size_t)b * n_out + d;
  unsigned short* op = hout + (size_t)b * n_out + d;
  const size_t hstride = (size_t)32 * n_out;

  float xt0, fr0, rr0, hw0, xt1, fr1, rr1, hw1;
  float xt2, fr2, rr2, hw2, xt3, fr3, rr3, hw3;

#define SRU_LOAD(S)                                                           \
  do {                                                                        \
    xt##S = bf2f(Up[0]);                                                      \
    fr##S = bf2f(Up[n_out]);                                                  \
    rr##S = bf2f(Up[2 * n_out]);                                              \
    hw##S = K4 ? bf2f(Up[3 * n_out]) : bf2f(*hp);                             \
    Up += lstride;                                                            \
    hp += hstride;                                                            \
  } while (0)

#define SRU_STEP(S)                                                           \
  do {                                                                        \
    const float f = 1.0f / (1.0f + __expf(-(fr##S + biasf)));                 \
    const float r = 1.0f / (1.0f + __expf(-(rr##S + biasr)));                 \
    c = f * c + (1.0f - f) * xt##S;                                           \
    const float e2 = __expf(2.0f * c);                                        \
    const float g = 1.0f - 2.0f / (e2 + 1.0f);                                \
    *op = f2bf(r * g + (1.0f - r) * hw##S);                                   \
    op += hstride;                                                            \
  } while (0)

  SRU_LOAD(0); SRU_LOAD(1); SRU_LOAD(2); SRU_LOAD(3);   // l = 0..3
  for (int l = 0; l < 124; l += 4) {                    // l = 0,4,...,120
    SRU_STEP(0); SRU_LOAD(0);                           // load l+4
    SRU_STEP(1); SRU_LOAD(1);
    SRU_STEP(2); SRU_LOAD(2);
    SRU_STEP(3); SRU_LOAD(3);
  }
  SRU_STEP(0); SRU_STEP(1); SRU_STEP(2); SRU_STEP(3);   // l = 124..127
#undef SRU_LOAD
#undef SRU_STEP
}

// ---------------------------------------------------------------------------
// Fused prep: emb->bf16 cvt + all 6 weight transposes (64x64 tiles ->
// 128B-per-instruction output rows).  256 thr/block.
// ---------------------------------------------------------------------------
__device__ __forceinline__ void transpose_tile64(const float* __restrict__ W,
                                                 unsigned short* __restrict__ Wt,
                                                 int K, int N, int bx, int by,
                                                 int tid) {
  __shared__ float tile[64][65];
  const int n0 = bx * 64, k0 = by * 64;
  const int tx = tid & 63, ty = tid >> 6;   // (64,4)
#pragma unroll
  for (int i = 0; i < 64; i += 4)
    tile[ty + i][tx] = W[(size_t)(k0 + ty + i) * N + n0 + tx];
  __syncthreads();
#pragma unroll
  for (int i = 0; i < 64; i += 4)
    Wt[(size_t)(n0 + ty + i) * K + k0 + tx] = f2bf(tile[tx][ty + i]);
}

__global__ void prep_k(const float* __restrict__ emb,
                       const float* __restrict__ W1,
                       const float* __restrict__ W2,
                       const float* __restrict__ W3,
                       unsigned short* __restrict__ embbf,
                       unsigned short* __restrict__ W1t,
                       unsigned short* __restrict__ W2t,
                       unsigned short* __restrict__ W3t) {
  const int blk = blockIdx.x;
  const int tid = threadIdx.x;
  if (blk < 16000) {                                   // cvt emb -> bf16
    const int i = blk * 256 + tid;
    const float4v v = ((const float4v*)emb)[i];
    u16x4 o;
    o.x = f2bf(v.x); o.y = f2bf(v.y); o.z = f2bf(v.z); o.w = f2bf(v.w);
    ((u16x4*)embbf)[i] = o;
  } else if (blk < 16512) {                            // W1: K=512 N=4096
    const int r = blk - 16000;                         // 64 x 8
    transpose_tile64(W1, W1t, 512, 4096, r & 63, r >> 6, tid);
  } else if (blk < 19584) {                            // W2[i]: K=1024 N=3072
    const int r = blk - 16512;
    const int i = r / 768, rr = r - i * 768;           // 48 x 16 per layer
    transpose_tile64(W2 + (size_t)i * 3145728, W2t + (size_t)i * 3145728,
                     1024, 3072, rr % 48, rr / 48, tid);
  } else {                                             // W3: K=1024 N=2048
    const int r = blk - 19584;                         // 32 x 16
    transpose_tile64(W3, W3t, 1024, 2048, r & 31, r >> 5, tid);
  }
}

extern "C" void kernel_launch(void* const* d_in, const int* in_sizes, int n_in,
                              void* d_out, int out_size, void* d_ws, size_t ws_size,
                              hipStream_t stream) {
  (void)in_sizes; (void)n_in; (void)out_size; (void)ws_size;
  const int*   x     = (const int*)d_in[0];
  const float* c1    = (const float*)d_in[1];
  const float* c2    = (const float*)d_in[2];
  const float* c3    = (const float*)d_in[3];
  const float* emb   = (const float*)d_in[4];
  const float* obias = (const float*)d_in[5];
  const float* W1    = (const float*)d_in[6];
  const float* b1    = (const float*)d_in[7];
  const float* W2    = (const float*)d_in[8];
  const float* b2    = (const float*)d_in[9];
  const float* W3    = (const float*)d_in[10];
  const float* b3    = (const float*)d_in[11];

  char* ws = (char*)d_ws;
  unsigned short* hbfA  = (unsigned short*)ws;                  //  8,388,608 B
  unsigned short* hbfB  = (unsigned short*)(ws + 8388608);      //  8,388,608 B
  unsigned short* embbf = (unsigned short*)(ws + 16777216);     // 32,768,000 B
  unsigned short* W1t   = (unsigned short*)(ws + 49545216);     //  4,194,304 B
  unsigned short* W2t   = (unsigned short*)(ws + 53739520);     // 25,165,824 B
  unsigned short* W3t   = (unsigned short*)(ws + 78905344);     //  4,194,304 B
  unsigned short* U = (unsigned short*)d_out;  // bf16 U scratch (<=34MB) in
                                               // d_out; logits overwrite it.

  // input prep in one launch (emb cvt + 6 transposes — independent)
  prep_k<<<20096, 256, 0, stream>>>(emb, W1, W2, W3, embbf, W1t, W2t, W3t);

  // ---- layer 1: (512 -> 1024, k=4): 32x32 = 1024 tiles, A = gather(embbf,x)
  gemm128<true, true><<<1024, 256, 0, stream>>>(embbf, W1t, U, nullptr, x,
                                                4096, 4096, 512, 32);
  scan_k<true><<<512, 64, 0, stream>>>(U, b1, c1, hbfB, hbfB, 1024);

  // ---- mid layers: 4x (1024 -> 1024, k=3): 32x24 = 768 tiles ----
  const unsigned short* hin = hbfB;
  unsigned short* hout = hbfA;
  for (int i = 0; i < 4; ++i) {
    gemm128<true, false><<<768, 256, 0, stream>>>(hin, W2t + (size_t)i * 3145728,
                                                  U, nullptr, nullptr,
                                                  4096, 3072, 1024, 32);
    scan_k<false><<<512, 64, 0, stream>>>(U, b2 + i * 2048, c2 + (size_t)i * 32768,
                                          hin, hout, 1024);
    const unsigned short* t = hin; hin = hout; hout = (unsigned short*)t;
  }

  // ---- final SRU: (1024 -> 512, k=4): 32x16 = 512 tiles ----
  gemm128<true, false><<<512, 256, 0, stream>>>(hin, W3t, U, nullptr, nullptr,
                                                4096, 2048, 1024, 32);
  scan_k<true><<<256, 64, 0, stream>>>(U, b3, c3, hout, hout, 512);

  // ---- logits: (4096 x 32000): 32x250 = 8000 tiles, fp32 + bias, NT-C ----
  gemm128<false, false><<<8000, 256, 0, stream>>>(hout, embbf, (float*)d_out,
                                                  obias, nullptr,
                                                  4096, 32000, 512, 32);
}

// Round 16
// 463.318 us; speedup vs baseline: 1.2496x; 1.1865x over previous
//
#include <hip/hip_runtime.h>

// ---------------------------------------------------------------------------
// SRU LM: emb-gather -> SRU(512->1024,k4) -> 4x SRU(1024,k3) -> SRU(1024->512,k4)
//         -> logits = h @ emb^T + bias
// L=128 B=32 E=512 D=1024 V=32000 MID=4
// Round 16 = round 13 (best, 544us) + CHUNKED-PARALLEL SCAN: L=128 split in
// 4 chunks x 32 steps; one 256-thr block holds 64 chains x 4 chunks.
// Pass1 computes per-chunk affine (A=prod f, B) [2 loads/step]; LDS combine
// (<=3 affine compositions, wave-uniform); pass2 re-scans with correct c0
// [4 loads/step, xt/f lines L2-hot].  Critical path 128 -> ~64 steps,
// occupancy 2 -> 8 waves/CU.  Round-15's tokr-register gather dropped
// (neutral); round-13 xs-LDS gather restored.
// GEMM: 128x128 tile (m97 structure), 16x16x32 MFMA, 256 thr, single-buffered
// 32KiB LDS; XCD-bijective swizzle, m-fastest tile order; write-combined
// epilogue; NT stores ONLY on logits fp32 C (round-14 lesson: U is re-read
// on-device, NT de-caches it).  U bf16 scratch in d_out.
// ---------------------------------------------------------------------------

typedef __attribute__((ext_vector_type(8))) __bf16 bf16x8;
typedef __attribute__((ext_vector_type(4))) float f32x4;
typedef __attribute__((ext_vector_type(4))) float float4v;
typedef __attribute__((ext_vector_type(4))) unsigned short u16x4;

__device__ __forceinline__ unsigned short f2bf(float f) {
  unsigned int u = __builtin_bit_cast(unsigned int, f);
  u += 0x7fffu + ((u >> 16) & 1u);          // RNE
  return (unsigned short)(u >> 16);
}
__device__ __forceinline__ float bf2f(unsigned short v) {
  unsigned int u = ((unsigned int)v) << 16;
  return __builtin_bit_cast(float, u);
}

#define GLDS16(SRC, DST)                                                      \
  __builtin_amdgcn_global_load_lds(                                           \
      (__attribute__((address_space(1))) void*)(SRC),                         \
      (__attribute__((address_space(3))) void*)(DST), 16, 0, 0)

// ---------------------------------------------------------------------------
// 128x128-tile GEMM (m97 structure).  C[m][n] = sum_k A[m][k]*B[n][k].
// A:(M,K) bf16, B:(N,K) bf16.  BF16OUT: C bf16 (normal stores — U re-read by
// scan) else C fp32 (+bias, NT stores — logits, host-only consumer).
// GATHER: A-row r sourced from A + x[m0+r]*K (token gather; A=embbf, K=512).
// M%128==0, N%128==0, K%64==0, grid%8==0.  256 thr = 4 waves (2x2),
// 64x64 out/wave (4x4 frags).  Single-buffered BK=64.
// LDS slot-swizzle: LDS[row][slot] = global 16B-slot (slot ^ (row&7)).
// Tile order m-fastest: consecutive wg on an XCD share B n-panel (L2).
// ---------------------------------------------------------------------------
template <bool BF16OUT, bool GATHER>
__global__ __launch_bounds__(256, 4)
void gemm128(const unsigned short* __restrict__ A,
             const unsigned short* __restrict__ B,
             void* __restrict__ Cv, const float* __restrict__ bias,
             const int* __restrict__ xrow,
             int M, int N, int K, int tiles_m) {
  __shared__ __align__(16) unsigned short As[128 * 64];
  __shared__ __align__(16) unsigned short Bs[128 * 64];
  __shared__ int xs[128];

  const int tid  = threadIdx.x;
  const int lane = tid & 63;
  const int wave = tid >> 6;
  const int wm = wave >> 1, wn = wave & 1;

  // bijective XCD swizzle (nwg % 8 == 0 for all our grids)
  const int nwg  = gridDim.x;
  const int orig = blockIdx.x;
  const int wg   = (orig & 7) * (nwg >> 3) + (orig >> 3);
  const int by = wg % tiles_m, bx = wg / tiles_m;   // m-fastest
  const int m0 = by * 128, n0 = bx * 128;

  if constexpr (GATHER) {
    if (tid < 128) xs[tid] = xrow[m0 + tid];
    __syncthreads();
  }

  const int srow  = lane >> 3;
  const int sslot = (lane & 7) ^ srow;
  const int fr = lane & 15;
  const int s0 = (lane >> 4) ^ (lane & 7);
  const int lg = lane >> 4;

  f32x4 acc[4][4] = {};

  const int ksteps = K >> 6;
  for (int ks = 0; ks < ksteps; ++ks) {
    const int k0 = ks << 6;
#pragma unroll
    for (int j = 0; j < 4; ++j) {
      const int rbase = (j * 4 + wave) * 8;          // wave-uniform
      const int r = rbase + srow;
      const unsigned short* sa;
      if constexpr (GATHER)
        sa = A + (size_t)xs[r] * K + k0 + sslot * 8;
      else
        sa = A + (size_t)(m0 + r) * K + k0 + sslot * 8;
      const unsigned short* sb = B + (size_t)(n0 + r) * K + k0 + sslot * 8;
      GLDS16(sa, &As[rbase * 64]);
      GLDS16(sb, &Bs[rbase * 64]);
    }
    __syncthreads();
#pragma unroll
    for (int kk = 0; kk < 2; ++kk) {
      const int slot = s0 ^ (kk << 2);
      bf16x8 a[4], b[4];
#pragma unroll
      for (int m = 0; m < 4; ++m)
        a[m] = *(const bf16x8*)&As[(wm * 64 + m * 16 + fr) * 64 + slot * 8];
#pragma unroll
      for (int n = 0; n < 4; ++n)
        b[n] = *(const bf16x8*)&Bs[(wn * 64 + n * 16 + fr) * 64 + slot * 8];
#pragma unroll
      for (int m = 0; m < 4; ++m)
#pragma unroll
        for (int n = 0; n < 4; ++n)
          acc[m][n] = __builtin_amdgcn_mfma_f32_16x16x32_bf16(a[m], b[n],
                                                              acc[m][n], 0, 0, 0);
    }
    __syncthreads();
  }

  // epilogue, write-combined order (m,r outer / n inner — round-8 lesson)
  if constexpr (BF16OUT) {
    unsigned short* C = (unsigned short*)Cv;
#pragma unroll
    for (int m = 0; m < 4; ++m) {
      const int row = m0 + wm * 64 + m * 16 + lg * 4;
#pragma unroll
      for (int r = 0; r < 4; ++r) {
        unsigned short* Crow = C + (size_t)(row + r) * N + n0 + wn * 64 + fr;
#pragma unroll
        for (int n = 0; n < 4; ++n)
          Crow[n * 16] = f2bf(acc[m][n][r]);
      }
    }
  } else {
    // fp32 path = logits only.  NT: C write-once, host-only reader; keep
    // L2/L3 for B panels instead of 524MB of C lines (round 13: -68us).
    float* C = (float*)Cv;
    float bv[4];
#pragma unroll
    for (int n = 0; n < 4; ++n)
      bv[n] = bias ? bias[n0 + wn * 64 + n * 16 + fr] : 0.0f;
#pragma unroll
    for (int m = 0; m < 4; ++m) {
      const int row = m0 + wm * 64 + m * 16 + lg * 4;
#pragma unroll
      for (int r = 0; r < 4; ++r) {
        float* Crow = C + (size_t)(row + r) * N + n0 + wn * 64 + fr;
#pragma unroll
        for (int n = 0; n < 4; ++n)
          __builtin_nontemporal_store(acc[m][n][r] + bv[n], &Crow[n * 16]);
      }
    }
  }
}

// ---------------------------------------------------------------------------
// Chunked-parallel SRU scan.  L=128 = 4 chunks x 32.  Block = 256 thr =
// 64 chains (lane) x 4 chunks (wave).  n_out % 64 == 0.
// c_l = f_l*c + (1-f_l)*x_l is affine in c: chunk -> (A,B), combine in LDS.
// ---------------------------------------------------------------------------
template <bool K4>
__global__ __launch_bounds__(256)
void scan_k(const unsigned short* __restrict__ U,
            const float* __restrict__ bias,
            const float* __restrict__ c0v,
            const unsigned short* __restrict__ hin,
            unsigned short* __restrict__ hout, int n_out) {
  __shared__ float lA[4][64], lB[4][64];
  const int lane = threadIdx.x & 63;           // chain within block
  const int ch   = threadIdx.x >> 6;           // chunk 0..3 (wave-uniform)
  const int idx  = blockIdx.x * 64 + lane;     // global chain (b,d)
  const int b = idx / n_out;
  const int d = idx - b * n_out;
  const float biasf = bias[d];
  const float biasr = bias[n_out + d];
  const int rowlen = (K4 ? 4 : 3) * n_out;
  const size_t lstride = (size_t)32 * rowlen;  // per-l stride
  const size_t hstride = (size_t)32 * n_out;
  const unsigned short* Up0 = U + (size_t)b * rowlen + d + (size_t)(ch * 32) * lstride;

  // ---- pass 1: per-chunk affine (A, B), 2 loads/step, 4-deep prefetch ----
  float A = 1.0f, Bv = 0.0f;
  {
    const unsigned short* p = Up0;
    float xt0, fr0, xt1, fr1, xt2, fr2, xt3, fr3;
#define P1_LOAD(S)                                                            \
    do { xt##S = bf2f(p[0]); fr##S = bf2f(p[n_out]); p += lstride; } while (0)
#define P1_STEP(S)                                                            \
    do {                                                                      \
      const float f = 1.0f / (1.0f + __expf(-(fr##S + biasf)));               \
      A *= f;  Bv = f * Bv + (1.0f - f) * xt##S;                              \
    } while (0)
    P1_LOAD(0); P1_LOAD(1); P1_LOAD(2); P1_LOAD(3);
    for (int s = 0; s < 28; s += 4) {
      P1_STEP(0); P1_LOAD(0);
      P1_STEP(1); P1_LOAD(1);
      P1_STEP(2); P1_LOAD(2);
      P1_STEP(3); P1_LOAD(3);
    }
    P1_STEP(0); P1_STEP(1); P1_STEP(2); P1_STEP(3);
#undef P1_LOAD
#undef P1_STEP
  }
  lA[ch][lane] = A;
  lB[ch][lane] = Bv;
  __syncthreads();

  // ---- combine: chunk-entry c = compose chunks 0..ch-1 onto c0 ----
  float c = c0v[idx];
  for (int i = 0; i < ch; ++i)                 // wave-uniform trip count
    c = lA[i][lane] * c + lB[i][lane];

  // ---- pass 2: re-scan 32 steps with correct c, write h ----
  {
    const unsigned short* p = Up0;
    const unsigned short* hp = hin + (size_t)b * n_out + d + (size_t)(ch * 32) * hstride;
    unsigned short* op = hout + (size_t)b * n_out + d + (size_t)(ch * 32) * hstride;
    float xt0, fr0, rr0, hw0, xt1, fr1, rr1, hw1;
    float xt2, fr2, rr2, hw2, xt3, fr3, rr3, hw3;
#define P2_LOAD(S)                                                            \
    do {                                                                      \
      xt##S = bf2f(p[0]);                                                     \
      fr##S = bf2f(p[n_out]);                                                 \
      rr##S = bf2f(p[2 * n_out]);                                             \
      hw##S = K4 ? bf2f(p[3 * n_out]) : bf2f(*hp);                            \
      p += lstride;                                                           \
      hp += hstride;                                                          \
    } while (0)
#define P2_STEP(S)                                                            \
    do {                                                                      \
      const float f = 1.0f / (1.0f + __expf(-(fr##S + biasf)));               \
      const float r = 1.0f / (1.0f + __expf(-(rr##S + biasr)));               \
      c = f * c + (1.0f - f) * xt##S;                                         \
      const float e2 = __expf(2.0f * c);                                      \
      const float g = 1.0f - 2.0f / (e2 + 1.0f);                              \
      *op = f2bf(r * g + (1.0f - r) * hw##S);                                 \
      op += hstride;                                                          \
    } while (0)
    P2_LOAD(0); P2_LOAD(1); P2_LOAD(2); P2_LOAD(3);
    for (int s = 0; s < 28; s += 4) {
      P2_STEP(0); P2_LOAD(0);
      P2_STEP(1); P2_LOAD(1);
      P2_STEP(2); P2_LOAD(2);
      P2_STEP(3); P2_LOAD(3);
    }
    P2_STEP(0); P2_STEP(1); P2_STEP(2); P2_STEP(3);
#undef P2_LOAD
#undef P2_STEP
  }
}

// ---------------------------------------------------------------------------
// Fused prep: emb->bf16 cvt + all 6 weight transposes (64x64 tiles ->
// 128B-per-instruction output rows).  256 thr/block.
// ---------------------------------------------------------------------------
__device__ __forceinline__ void transpose_tile64(const float* __restrict__ W,
                                                 unsigned short* __restrict__ Wt,
                                                 int K, int N, int bx, int by,
                                                 int tid) {
  __shared__ float tile[64][65];
  const int n0 = bx * 64, k0 = by * 64;
  const int tx = tid & 63, ty = tid >> 6;   // (64,4)
#pragma unroll
  for (int i = 0; i < 64; i += 4)
    tile[ty + i][tx] = W[(size_t)(k0 + ty + i) * N + n0 + tx];
  __syncthreads();
#pragma unroll
  for (int i = 0; i < 64; i += 4)
    Wt[(size_t)(n0 + ty + i) * K + k0 + tx] = f2bf(tile[tx][ty + i]);
}

__global__ void prep_k(const float* __restrict__ emb,
                       const float* __restrict__ W1,
                       const float* __restrict__ W2,
                       const float* __restrict__ W3,
                       unsigned short* __restrict__ embbf,
                       unsigned short* __restrict__ W1t,
                       unsigned short* __restrict__ W2t,
                       unsigned short* __restrict__ W3t) {
  const int blk = blockIdx.x;
  const int tid = threadIdx.x;
  if (blk < 16000) {                                   // cvt emb -> bf16
    const int i = blk * 256 + tid;
    const float4v v = ((const float4v*)emb)[i];
    u16x4 o;
    o.x = f2bf(v.x); o.y = f2bf(v.y); o.z = f2bf(v.z); o.w = f2bf(v.w);
    ((u16x4*)embbf)[i] = o;
  } else if (blk < 16512) {                            // W1: K=512 N=4096
    const int r = blk - 16000;                         // 64 x 8
    transpose_tile64(W1, W1t, 512, 4096, r & 63, r >> 6, tid);
  } else if (blk < 19584) {                            // W2[i]: K=1024 N=3072
    const int r = blk - 16512;
    const int i = r / 768, rr = r - i * 768;           // 48 x 16 per layer
    transpose_tile64(W2 + (size_t)i * 3145728, W2t + (size_t)i * 3145728,
                     1024, 3072, rr % 48, rr / 48, tid);
  } else {                                             // W3: K=1024 N=2048
    const int r = blk - 19584;                         // 32 x 16
    transpose_tile64(W3, W3t, 1024, 2048, r & 31, r >> 5, tid);
  }
}

extern "C" void kernel_launch(void* const* d_in, const int* in_sizes, int n_in,
                              void* d_out, int out_size, void* d_ws, size_t ws_size,
                              hipStream_t stream) {
  (void)in_sizes; (void)n_in; (void)out_size; (void)ws_size;
  const int*   x     = (const int*)d_in[0];
  const float* c1    = (const float*)d_in[1];
  const float* c2    = (const float*)d_in[2];
  const float* c3    = (const float*)d_in[3];
  const float* emb   = (const float*)d_in[4];
  const float* obias = (const float*)d_in[5];
  const float* W1    = (const float*)d_in[6];
  const float* b1    = (const float*)d_in[7];
  const float* W2    = (const float*)d_in[8];
  const float* b2    = (const float*)d_in[9];
  const float* W3    = (const float*)d_in[10];
  const float* b3    = (const float*)d_in[11];

  char* ws = (char*)d_ws;
  unsigned short* hbfA  = (unsigned short*)ws;                  //  8,388,608 B
  unsigned short* hbfB  = (unsigned short*)(ws + 8388608);      //  8,388,608 B
  unsigned short* embbf = (unsigned short*)(ws + 16777216);     // 32,768,000 B
  unsigned short* W1t   = (unsigned short*)(ws + 49545216);     //  4,194,304 B
  unsigned short* W2t   = (unsigned short*)(ws + 53739520);     // 25,165,824 B
  unsigned short* W3t   = (unsigned short*)(ws + 78905344);     //  4,194,304 B
  unsigned short* U = (unsigned short*)d_out;  // bf16 U scratch (<=34MB) in
                                               // d_out; logits overwrite it.

  // input prep in one launch (emb cvt + 6 transposes — independent)
  prep_k<<<20096, 256, 0, stream>>>(emb, W1, W2, W3, embbf, W1t, W2t, W3t);

  // ---- layer 1: (512 -> 1024, k=4): 32x32 = 1024 tiles, A = gather(embbf,x)
  gemm128<true, true><<<1024, 256, 0, stream>>>(embbf, W1t, U, nullptr, x,
                                                4096, 4096, 512, 32);
  scan_k<true><<<512, 256, 0, stream>>>(U, b1, c1, hbfB, hbfB, 1024);

  // ---- mid layers: 4x (1024 -> 1024, k=3): 32x24 = 768 tiles ----
  const unsigned short* hin = hbfB;
  unsigned short* hout = hbfA;
  for (int i = 0; i < 4; ++i) {
    gemm128<true, false><<<768, 256, 0, stream>>>(hin, W2t + (size_t)i * 3145728,
                                                  U, nullptr, nullptr,
                                                  4096, 3072, 1024, 32);
    scan_k<false><<<512, 256, 0, stream>>>(U, b2 + i * 2048, c2 + (size_t)i * 32768,
                                           hin, hout, 1024);
    const unsigned short* t = hin; hin = hout; hout = (unsigned short*)t;
  }

  // ---- final SRU: (1024 -> 512, k=4): 32x16 = 512 tiles ----
  gemm128<true, false><<<512, 256, 0, stream>>>(hin, W3t, U, nullptr, nullptr,
                                                4096, 2048, 1024, 32);
  scan_k<true><<<256, 256, 0, stream>>>(U, b3, c3, hout, hout, 512);

  // ---- logits: (4096 x 32000): 32x250 = 8000 tiles, fp32 + bias, NT-C ----
  gemm128<false, false><<<8000, 256, 0, stream>>>(hout, embbf, (float*)d_out,
                                                  obias, nullptr,
                                                  4096, 32000, 512, 32);
}

// Round 17
// 435.744 us; speedup vs baseline: 1.3286x; 1.0633x over previous
//
#include <hip/hip_runtime.h>

// ---------------------------------------------------------------------------
// SRU LM: emb-gather -> SRU(512->1024,k4) -> 4x SRU(1024,k3) -> SRU(1024->512,k4)
//         -> logits = h @ emb^T + bias
// L=128 B=32 E=512 D=1024 V=32000 MID=4
// Round 17 = round 16 (463us) + SCAN v3: 8 chunks x 16 steps (512-thr block,
// 64 chains x 8 chunks); pass1 carries f and w=(1-f)*xt in 32 unrolled regs
// -> pass2 only loads rr/hw (2/step) and skips the f-sigmoid recompute.
// Critical path 64 -> 32 steps.  Affine chunk combine in LDS as r16.
// GEMM: 128x128 tile (m97 structure), 16x16x32 MFMA, 256 thr, single-buffered
// 32KiB LDS; XCD-bijective swizzle, m-fastest tile order; write-combined
// epilogue; NT stores ONLY on logits fp32 C (U is re-read on-device).
// U bf16 scratch in d_out (logits overwrite at end).
// ---------------------------------------------------------------------------

typedef __attribute__((ext_vector_type(8))) __bf16 bf16x8;
typedef __attribute__((ext_vector_type(4))) float f32x4;
typedef __attribute__((ext_vector_type(4))) float float4v;
typedef __attribute__((ext_vector_type(4))) unsigned short u16x4;

__device__ __forceinline__ unsigned short f2bf(float f) {
  unsigned int u = __builtin_bit_cast(unsigned int, f);
  u += 0x7fffu + ((u >> 16) & 1u);          // RNE
  return (unsigned short)(u >> 16);
}
__device__ __forceinline__ float bf2f(unsigned short v) {
  unsigned int u = ((unsigned int)v) << 16;
  return __builtin_bit_cast(float, u);
}

#define GLDS16(SRC, DST)                                                      \
  __builtin_amdgcn_global_load_lds(                                           \
      (__attribute__((address_space(1))) void*)(SRC),                         \
      (__attribute__((address_space(3))) void*)(DST), 16, 0, 0)

// ---------------------------------------------------------------------------
// 128x128-tile GEMM (m97 structure).  C[m][n] = sum_k A[m][k]*B[n][k].
// A:(M,K) bf16, B:(N,K) bf16.  BF16OUT: C bf16 (normal stores — U re-read by
// scan) else C fp32 (+bias, NT stores — logits, host-only consumer).
// GATHER: A-row r sourced from A + x[m0+r]*K (token gather; A=embbf, K=512).
// M%128==0, N%128==0, K%64==0, grid%8==0.  256 thr = 4 waves (2x2),
// 64x64 out/wave (4x4 frags).  Single-buffered BK=64.
// LDS slot-swizzle: LDS[row][slot] = global 16B-slot (slot ^ (row&7)).
// Tile order m-fastest: consecutive wg on an XCD share B n-panel (L2).
// ---------------------------------------------------------------------------
template <bool BF16OUT, bool GATHER>
__global__ __launch_bounds__(256, 4)
void gemm128(const unsigned short* __restrict__ A,
             const unsigned short* __restrict__ B,
             void* __restrict__ Cv, const float* __restrict__ bias,
             const int* __restrict__ xrow,
             int M, int N, int K, int tiles_m) {
  __shared__ __align__(16) unsigned short As[128 * 64];
  __shared__ __align__(16) unsigned short Bs[128 * 64];
  __shared__ int xs[128];

  const int tid  = threadIdx.x;
  const int lane = tid & 63;
  const int wave = tid >> 6;
  const int wm = wave >> 1, wn = wave & 1;

  // bijective XCD swizzle (nwg % 8 == 0 for all our grids)
  const int nwg  = gridDim.x;
  const int orig = blockIdx.x;
  const int wg   = (orig & 7) * (nwg >> 3) + (orig >> 3);
  const int by = wg % tiles_m, bx = wg / tiles_m;   // m-fastest
  const int m0 = by * 128, n0 = bx * 128;

  if constexpr (GATHER) {
    if (tid < 128) xs[tid] = xrow[m0 + tid];
    __syncthreads();
  }

  const int srow  = lane >> 3;
  const int sslot = (lane & 7) ^ srow;
  const int fr = lane & 15;
  const int s0 = (lane >> 4) ^ (lane & 7);
  const int lg = lane >> 4;

  f32x4 acc[4][4] = {};

  const int ksteps = K >> 6;
  for (int ks = 0; ks < ksteps; ++ks) {
    const int k0 = ks << 6;
#pragma unroll
    for (int j = 0; j < 4; ++j) {
      const int rbase = (j * 4 + wave) * 8;          // wave-uniform
      const int r = rbase + srow;
      const unsigned short* sa;
      if constexpr (GATHER)
        sa = A + (size_t)xs[r] * K + k0 + sslot * 8;
      else
        sa = A + (size_t)(m0 + r) * K + k0 + sslot * 8;
      const unsigned short* sb = B + (size_t)(n0 + r) * K + k0 + sslot * 8;
      GLDS16(sa, &As[rbase * 64]);
      GLDS16(sb, &Bs[rbase * 64]);
    }
    __syncthreads();
#pragma unroll
    for (int kk = 0; kk < 2; ++kk) {
      const int slot = s0 ^ (kk << 2);
      bf16x8 a[4], b[4];
#pragma unroll
      for (int m = 0; m < 4; ++m)
        a[m] = *(const bf16x8*)&As[(wm * 64 + m * 16 + fr) * 64 + slot * 8];
#pragma unroll
      for (int n = 0; n < 4; ++n)
        b[n] = *(const bf16x8*)&Bs[(wn * 64 + n * 16 + fr) * 64 + slot * 8];
#pragma unroll
      for (int m = 0; m < 4; ++m)
#pragma unroll
        for (int n = 0; n < 4; ++n)
          acc[m][n] = __builtin_amdgcn_mfma_f32_16x16x32_bf16(a[m], b[n],
                                                              acc[m][n], 0, 0, 0);
    }
    __syncthreads();
  }

  // epilogue, write-combined order (m,r outer / n inner — round-8 lesson)
  if constexpr (BF16OUT) {
    unsigned short* C = (unsigned short*)Cv;
#pragma unroll
    for (int m = 0; m < 4; ++m) {
      const int row = m0 + wm * 64 + m * 16 + lg * 4;
#pragma unroll
      for (int r = 0; r < 4; ++r) {
        unsigned short* Crow = C + (size_t)(row + r) * N + n0 + wn * 64 + fr;
#pragma unroll
        for (int n = 0; n < 4; ++n)
          Crow[n * 16] = f2bf(acc[m][n][r]);
      }
    }
  } else {
    // fp32 path = logits only.  NT: C write-once, host-only reader; keep
    // L2/L3 for B panels instead of 524MB of C lines (round 13: -68us).
    float* C = (float*)Cv;
    float bv[4];
#pragma unroll
    for (int n = 0; n < 4; ++n)
      bv[n] = bias ? bias[n0 + wn * 64 + n * 16 + fr] : 0.0f;
#pragma unroll
    for (int m = 0; m < 4; ++m) {
      const int row = m0 + wm * 64 + m * 16 + lg * 4;
#pragma unroll
      for (int r = 0; r < 4; ++r) {
        float* Crow = C + (size_t)(row + r) * N + n0 + wn * 64 + fr;
#pragma unroll
        for (int n = 0; n < 4; ++n)
          __builtin_nontemporal_store(acc[m][n][r] + bv[n], &Crow[n * 16]);
      }
    }
  }
}

// ---------------------------------------------------------------------------
// Chunked-parallel SRU scan v3.  L=128 = 8 chunks x 16.  Block = 512 thr =
// 64 chains (lane) x 8 chunks (wave).  n_out % 64 == 0.
// Pass1: per-chunk affine (A,B), carrying f[s], w[s]=(1-f)*xt in registers
// (fully unrolled -> constant indices).  LDS combine.  Pass2: c = f*c + w,
// loads only rr/hw.
// ---------------------------------------------------------------------------
template <bool K4>
__global__ __launch_bounds__(512)
void scan_k(const unsigned short* __restrict__ U,
            const float* __restrict__ bias,
            const float* __restrict__ c0v,
            const unsigned short* __restrict__ hin,
            unsigned short* __restrict__ hout, int n_out) {
  __shared__ float lA[8][64], lB[8][64];
  const int lane = threadIdx.x & 63;           // chain within block
  const int ch   = threadIdx.x >> 6;           // chunk 0..7 (wave-uniform)
  const int idx  = blockIdx.x * 64 + lane;     // global chain (b,d)
  const int b = idx / n_out;
  const int d = idx - b * n_out;
  const float biasf = bias[d];
  const float biasr = bias[n_out + d];
  const int rowlen = (K4 ? 4 : 3) * n_out;
  const size_t lstride = (size_t)32 * rowlen;  // per-l stride
  const size_t hstride = (size_t)32 * n_out;
  const unsigned short* Up0 = U + (size_t)b * rowlen + d + (size_t)(ch * 16) * lstride;

  // ---- pass 1: per-chunk affine (A, B); carry f, w in registers ----
  float fv[16], wv[16];                        // constant-indexed after unroll
  float A = 1.0f, Bv = 0.0f;
  {
    const unsigned short* p = Up0;
#pragma unroll
    for (int s = 0; s < 16; ++s) {
      const float xt   = bf2f(p[0]);
      const float fraw = bf2f(p[n_out]);
      p += lstride;
      const float f = 1.0f / (1.0f + __expf(-(fraw + biasf)));
      fv[s] = f;
      wv[s] = (1.0f - f) * xt;
      A *= f;
      Bv = f * Bv + wv[s];
    }
  }
  lA[ch][lane] = A;
  lB[ch][lane] = Bv;
  __syncthreads();

  // ---- combine: chunk-entry c = compose chunks 0..ch-1 onto c0 ----
  float c = c0v[idx];
  for (int i = 0; i < ch; ++i)                 // wave-uniform trip count
    c = lA[i][lane] * c + lB[i][lane];

  // ---- pass 2: 16 steps with carried f/w; load only rr, hw ----
  {
    const unsigned short* p = Up0;
    const unsigned short* hp = hin + (size_t)b * n_out + d + (size_t)(ch * 16) * hstride;
    unsigned short* op = hout + (size_t)b * n_out + d + (size_t)(ch * 16) * hstride;
#pragma unroll
    for (int s = 0; s < 16; ++s) {
      const float rr = bf2f(p[2 * n_out]);
      const float hw = K4 ? bf2f(p[3 * n_out]) : bf2f(*hp);
      p += lstride;
      hp += hstride;
      c = fv[s] * c + wv[s];
      const float r = 1.0f / (1.0f + __expf(-(rr + biasr)));
      const float e2 = __expf(2.0f * c);
      const float g = 1.0f - 2.0f / (e2 + 1.0f);
      *op = f2bf(r * g + (1.0f - r) * hw);
      op += hstride;
    }
  }
}

// ---------------------------------------------------------------------------
// Fused prep: emb->bf16 cvt + all 6 weight transposes (64x64 tiles ->
// 128B-per-instruction output rows).  256 thr/block.
// ---------------------------------------------------------------------------
__device__ __forceinline__ void transpose_tile64(const float* __restrict__ W,
                                                 unsigned short* __restrict__ Wt,
                                                 int K, int N, int bx, int by,
                                                 int tid) {
  __shared__ float tile[64][65];
  const int n0 = bx * 64, k0 = by * 64;
  const int tx = tid & 63, ty = tid >> 6;   // (64,4)
#pragma unroll
  for (int i = 0; i < 64; i += 4)
    tile[ty + i][tx] = W[(size_t)(k0 + ty + i) * N + n0 + tx];
  __syncthreads();
#pragma unroll
  for (int i = 0; i < 64; i += 4)
    Wt[(size_t)(n0 + ty + i) * K + k0 + tx] = f2bf(tile[tx][ty + i]);
}

__global__ void prep_k(const float* __restrict__ emb,
                       const float* __restrict__ W1,
                       const float* __restrict__ W2,
                       const float* __restrict__ W3,
                       unsigned short* __restrict__ embbf,
                       unsigned short* __restrict__ W1t,
                       unsigned short* __restrict__ W2t,
                       unsigned short* __restrict__ W3t) {
  const int blk = blockIdx.x;
  const int tid = threadIdx.x;
  if (blk < 16000) {                                   // cvt emb -> bf16
    const int i = blk * 256 + tid;
    const float4v v = ((const float4v*)emb)[i];
    u16x4 o;
    o.x = f2bf(v.x); o.y = f2bf(v.y); o.z = f2bf(v.z); o.w = f2bf(v.w);
    ((u16x4*)embbf)[i] = o;
  } else if (blk < 16512) {                            // W1: K=512 N=4096
    const int r = blk - 16000;                         // 64 x 8
    transpose_tile64(W1, W1t, 512, 4096, r & 63, r >> 6, tid);
  } else if (blk < 19584) {                            // W2[i]: K=1024 N=3072
    const int r = blk - 16512;
    const int i = r / 768, rr = r - i * 768;           // 48 x 16 per layer
    transpose_tile64(W2 + (size_t)i * 3145728, W2t + (size_t)i * 3145728,
                     1024, 3072, rr % 48, rr / 48, tid);
  } else {                                             // W3: K=1024 N=2048
    const int r = blk - 19584;                         // 32 x 16
    transpose_tile64(W3, W3t, 1024, 2048, r & 31, r >> 5, tid);
  }
}

extern "C" void kernel_launch(void* const* d_in, const int* in_sizes, int n_in,
                              void* d_out, int out_size, void* d_ws, size_t ws_size,
                              hipStream_t stream) {
  (void)in_sizes; (void)n_in; (void)out_size; (void)ws_size;
  const int*   x     = (const int*)d_in[0];
  const float* c1    = (const float*)d_in[1];
  const float* c2    = (const float*)d_in[2];
  const float* c3    = (const float*)d_in[3];
  const float* emb   = (const float*)d_in[4];
  const float* obias = (const float*)d_in[5];
  const float* W1    = (const float*)d_in[6];
  const float* b1    = (const float*)d_in[7];
  const float* W2    = (const float*)d_in[8];
  const float* b2    = (const float*)d_in[9];
  const float* W3    = (const float*)d_in[10];
  const float* b3    = (const float*)d_in[11];

  char* ws = (char*)d_ws;
  unsigned short* hbfA  = (unsigned short*)ws;                  //  8,388,608 B
  unsigned short* hbfB  = (unsigned short*)(ws + 8388608);      //  8,388,608 B
  unsigned short* embbf = (unsigned short*)(ws + 16777216);     // 32,768,000 B
  unsigned short* W1t   = (unsigned short*)(ws + 49545216);     //  4,194,304 B
  unsigned short* W2t   = (unsigned short*)(ws + 53739520);     // 25,165,824 B
  unsigned short* W3t   = (unsigned short*)(ws + 78905344);     //  4,194,304 B
  unsigned short* U = (unsigned short*)d_out;  // bf16 U scratch (<=34MB) in
                                               // d_out; logits overwrite it.

  // input prep in one launch (emb cvt + 6 transposes — independent)
  prep_k<<<20096, 256, 0, stream>>>(emb, W1, W2, W3, embbf, W1t, W2t, W3t);

  // ---- layer 1: (512 -> 1024, k=4): 32x32 = 1024 tiles, A = gather(embbf,x)
  gemm128<true, true><<<1024, 256, 0, stream>>>(embbf, W1t, U, nullptr, x,
                                                4096, 4096, 512, 32);
  scan_k<true><<<512, 512, 0, stream>>>(U, b1, c1, hbfB, hbfB, 1024);

  // ---- mid layers: 4x (1024 -> 1024, k=3): 32x24 = 768 tiles ----
  const unsigned short* hin = hbfB;
  unsigned short* hout = hbfA;
  for (int i = 0; i < 4; ++i) {
    gemm128<true, false><<<768, 256, 0, stream>>>(hin, W2t + (size_t)i * 3145728,
                                                  U, nullptr, nullptr,
                                                  4096, 3072, 1024, 32);
    scan_k<false><<<512, 512, 0, stream>>>(U, b2 + i * 2048, c2 + (size_t)i * 32768,
                                           hin, hout, 1024);
    const unsigned short* t = hin; hin = hout; hout = (unsigned short*)t;
  }

  // ---- final SRU: (1024 -> 512, k=4): 32x16 = 512 tiles ----
  gemm128<true, false><<<512, 256, 0, stream>>>(hin, W3t, U, nullptr, nullptr,
                                                4096, 2048, 1024, 32);
  scan_k<true><<<256, 512, 0, stream>>>(U, b3, c3, hout, hout, 512);

  // ---- logits: (4096 x 32000): 32x250 = 8000 tiles, fp32 + bias, NT-C ----
  gemm128<false, false><<<8000, 256, 0, stream>>>(hout, embbf, (float*)d_out,
                                                  obias, nullptr,
                                                  4096, 32000, 512, 32);
}